// Round 1
// baseline (3438.670 us; speedup 1.0000x reference)
//
#include <hip/hip_runtime.h>

#define N_NODES 100000
#define N_EDGES 1600000
#define HID 64
#define BN_EPS 1e-5f

#define GEMM_BLOCKS 1024   // 256 threads = 4 waves each

__device__ __forceinline__ float bcastf(float v, int k) {
    // uniform broadcast of lane k's value -> SGPR operand for the FMA
    return __int_as_float(__builtin_amdgcn_readlane(__float_as_int(v), k));
}

// -------- scatter-add: agg[dst] += xin[src], 16 threads per edge ---------
__global__ __launch_bounds__(256) void scatter_add_kernel(
        const float* __restrict__ xin, const int* __restrict__ src,
        const int* __restrict__ dst, float* __restrict__ agg) {
    int tid = blockIdx.x * blockDim.x + threadIdx.x;
    int e = tid >> 4;
    if (e >= N_EDGES) return;
    int q = (tid & 15) << 2;
    int s = src[e], d = dst[e];
    float4 v = *reinterpret_cast<const float4*>(xin + (size_t)s * HID + q);
    float* o = agg + (size_t)d * HID + q;
    atomicAdd(o + 0, v.x);
    atomicAdd(o + 1, v.y);
    atomicAdd(o + 2, v.z);
    atomicAdd(o + 3, v.w);
}

// -------- fused row-GEMM: one wave per row, W column in 64 VGPRs ---------
// out[r][c] = (opt post-relu)( sum_k pre(in[r][k]) * W[k][c] + bias[c]/out[r][c] )
template<bool PRE_BN, bool POST_RELU, bool ACCUM, bool STATS>
__global__ __launch_bounds__(256) void fused_gemm_kernel(
        const float* __restrict__ in, const float* __restrict__ W,
        const float* __restrict__ bias, const float* __restrict__ scale,
        const float* __restrict__ shift, float* __restrict__ out,
        float* __restrict__ stats_partial, int nrows) {
    const int lane = threadIdx.x & 63;
    const int w    = threadIdx.x >> 6;

    float wcol[64];
#pragma unroll
    for (int k = 0; k < 64; ++k) wcol[k] = W[k * HID + lane];

    float sc = 0.f, sh = 0.f, bs = 0.f;
    if (PRE_BN) { sc = scale[lane]; sh = shift[lane]; }
    if (!ACCUM) bs = bias[lane];

    float ssum = 0.f, ssumsq = 0.f;
    const int gw = blockIdx.x * 4 + w;
    const int stride = gridDim.x * 4;
    for (int r = gw; r < nrows; r += stride) {
        float v = in[(size_t)r * HID + lane];
        if (PRE_BN) v = fmaxf(fmaf(sc, v, sh), 0.f);
        float acc = ACCUM ? out[(size_t)r * HID + lane] : bs;
#pragma unroll
        for (int k = 0; k < 64; ++k)
            acc = fmaf(bcastf(v, k), wcol[k], acc);
        if (POST_RELU) acc = fmaxf(acc, 0.f);
        out[(size_t)r * HID + lane] = acc;
        if (STATS) { ssum += acc; ssumsq += acc * acc; }
    }

    if (STATS) {
        __shared__ float red[2][256];
        red[0][threadIdx.x] = ssum;
        red[1][threadIdx.x] = ssumsq;
        __syncthreads();
        if (w == 0) {
            float s = red[0][lane] + red[0][64 + lane] + red[0][128 + lane] + red[0][192 + lane];
            float q = red[1][lane] + red[1][64 + lane] + red[1][128 + lane] + red[1][192 + lane];
            stats_partial[(size_t)blockIdx.x * 128 + lane]       = s;
            stats_partial[(size_t)blockIdx.x * 128 + 64 + lane]  = q;
        }
    }
}

// -------- BN finalize: reduce partials -> scale/shift --------------------
__global__ __launch_bounds__(64) void bn_finalize_kernel(
        const float* __restrict__ stats_partial, int nblocks,
        const float* __restrict__ gamma, const float* __restrict__ beta,
        float* __restrict__ scale, float* __restrict__ shift) {
    int c = threadIdx.x;  // 64 threads
    float s = 0.f, q = 0.f;
    for (int b = 0; b < nblocks; ++b) {
        s += stats_partial[(size_t)b * 128 + c];
        q += stats_partial[(size_t)b * 128 + 64 + c];
    }
    float mean = s / (float)N_NODES;
    float var  = q / (float)N_NODES - mean * mean;
    float scl  = gamma[c] * rsqrtf(var + BN_EPS);
    scale[c] = scl;
    shift[c] = beta[c] - mean * scl;
}

extern "C" void kernel_launch(void* const* d_in, const int* in_sizes, int n_in,
                              void* d_out, int out_size, void* d_ws, size_t ws_size,
                              hipStream_t stream) {
    const float* x    = (const float*)d_in[0];
    const int*   ei   = (const int*)d_in[1];
    const int*   src  = ei;
    const int*   dst  = ei + N_EDGES;
    // d_in[2] = edge_attr (ignored)
    const float* W1_0 = (const float*)d_in[3];
    const float* b1_0 = (const float*)d_in[4];
    const float* g_0  = (const float*)d_in[5];
    const float* be_0 = (const float*)d_in[6];
    const float* W2_0 = (const float*)d_in[7];
    const float* b2_0 = (const float*)d_in[8];
    const float* W1_1 = (const float*)d_in[9];
    const float* b1_1 = (const float*)d_in[10];
    const float* g_1  = (const float*)d_in[11];
    const float* be_1 = (const float*)d_in[12];
    const float* W2_1 = (const float*)d_in[13];
    const float* b2_1 = (const float*)d_in[14];
    const float* Wjk  = (const float*)d_in[15];
    const float* bjk  = (const float*)d_in[16];

    const size_t FEAT = (size_t)N_NODES * HID;
    const size_t FEAT_BYTES = FEAT * sizeof(float);

    float* agg   = (float*)d_ws;          // N*64, also holds pre-BN h in-place
    float* h1    = agg + FEAT;
    float* h2    = h1 + FEAT;
    float* stats = h2 + FEAT;             // GEMM_BLOCKS * 128
    float* scale = stats + (size_t)GEMM_BLOCKS * 128;
    float* shift = scale + 64;
    float* out   = (float*)d_out;

    const int scatter_blocks = (N_EDGES * 16) / 256;   // 100000

    // ---------------- layer 0 ----------------
    hipMemcpyAsync(agg, x, FEAT_BYTES, hipMemcpyDeviceToDevice, stream);
    scatter_add_kernel<<<scatter_blocks, 256, 0, stream>>>(x, src, dst, agg);
    // h = agg @ W1_0 + b1_0  (in-place on agg; row-self-contained per wave)
    fused_gemm_kernel<false, false, false, true><<<GEMM_BLOCKS, 256, 0, stream>>>(
        agg, W1_0, b1_0, nullptr, nullptr, agg, stats, N_NODES);
    bn_finalize_kernel<<<1, 64, 0, stream>>>(stats, GEMM_BLOCKS, g_0, be_0, scale, shift);
    // h1 = relu( relu(bn(h)) @ W2_0 + b2_0 )
    fused_gemm_kernel<true, true, false, false><<<GEMM_BLOCKS, 256, 0, stream>>>(
        agg, W2_0, b2_0, scale, shift, h1, nullptr, N_NODES);

    // ---------------- layer 1 ----------------
    hipMemcpyAsync(agg, h1, FEAT_BYTES, hipMemcpyDeviceToDevice, stream);
    scatter_add_kernel<<<scatter_blocks, 256, 0, stream>>>(h1, src, dst, agg);
    fused_gemm_kernel<false, false, false, true><<<GEMM_BLOCKS, 256, 0, stream>>>(
        agg, W1_1, b1_1, nullptr, nullptr, agg, stats, N_NODES);
    bn_finalize_kernel<<<1, 64, 0, stream>>>(stats, GEMM_BLOCKS, g_1, be_1, scale, shift);
    fused_gemm_kernel<true, true, false, false><<<GEMM_BLOCKS, 256, 0, stream>>>(
        agg, W2_1, b2_1, scale, shift, h2, nullptr, N_NODES);

    // ---------------- jump head: out = [x|h1|h2] @ Wjk + bjk ----------------
    fused_gemm_kernel<false, false, false, false><<<GEMM_BLOCKS, 256, 0, stream>>>(
        x, Wjk, bjk, nullptr, nullptr, out, nullptr, N_NODES);
    fused_gemm_kernel<false, false, true, false><<<GEMM_BLOCKS, 256, 0, stream>>>(
        h1, Wjk + (size_t)64 * HID, nullptr, nullptr, nullptr, out, nullptr, N_NODES);
    fused_gemm_kernel<false, false, true, false><<<GEMM_BLOCKS, 256, 0, stream>>>(
        h2, Wjk + (size_t)128 * HID, nullptr, nullptr, nullptr, out, nullptr, N_NODES);
}

// Round 2
// 1551.673 us; speedup vs baseline: 2.2161x; 2.2161x over previous
//
#include <hip/hip_runtime.h>

#define N_NODES 100000
#define N_EDGES 1600000
#define HID 64
#define BN_EPS 1e-5f

#define GEMM_BLOCKS 1024     // 256 threads = 4 waves each
#define GATHER_BLOCKS 2048
#define SCAN_CHUNK 512
#define SCAN_BLOCKS ((N_NODES + SCAN_CHUNK - 1) / SCAN_CHUNK)   // 196

__device__ __forceinline__ float bcastf(float v, int k) {
    return __int_as_float(__builtin_amdgcn_readlane(__float_as_int(v), k));
}

// ---------------- CSR build ----------------
__global__ __launch_bounds__(256) void hist_kernel(
        const int* __restrict__ dst, int* __restrict__ deg) {
    int e = blockIdx.x * 256 + threadIdx.x;
    if (e < N_EDGES) atomicAdd(&deg[dst[e]], 1);
}

// block-local exclusive scan of 512 elements (2 per thread)
__global__ __launch_bounds__(256) void scan_partial_kernel(
        const int* __restrict__ deg, int* __restrict__ off, int* __restrict__ bsums) {
    __shared__ int sd[256];
    int t = threadIdx.x;
    int base = blockIdx.x * SCAN_CHUNK;
    int i0 = base + 2 * t, i1 = i0 + 1;
    int d0 = (i0 < N_NODES) ? deg[i0] : 0;
    int d1 = (i1 < N_NODES) ? deg[i1] : 0;
    sd[t] = d0 + d1;
    __syncthreads();
    for (int o = 1; o < 256; o <<= 1) {
        int v = (t >= o) ? sd[t - o] : 0;
        __syncthreads();
        sd[t] += v;
        __syncthreads();
    }
    int excl = sd[t] - (d0 + d1);   // exclusive within block
    if (i0 < N_NODES) off[i0] = excl;
    if (i1 < N_NODES) off[i1] = excl + d0;
    if (t == 255) bsums[blockIdx.x] = sd[255];
}

__global__ __launch_bounds__(256) void scan_bsums_kernel(int* __restrict__ bsums) {
    __shared__ int sd[256];
    int t = threadIdx.x;
    int v = (t < SCAN_BLOCKS) ? bsums[t] : 0;
    sd[t] = v;
    __syncthreads();
    for (int o = 1; o < 256; o <<= 1) {
        int u = (t >= o) ? sd[t - o] : 0;
        __syncthreads();
        sd[t] += u;
        __syncthreads();
    }
    if (t < SCAN_BLOCKS) bsums[t] = sd[t] - v;   // exclusive
}

__global__ __launch_bounds__(256) void scan_addback_kernel(
        int* __restrict__ off, int* __restrict__ cursor, const int* __restrict__ bsums) {
    int t = threadIdx.x;
    int b = bsums[blockIdx.x];
    int base = blockIdx.x * SCAN_CHUNK;
    int i0 = base + 2 * t, i1 = i0 + 1;
    if (i0 < N_NODES) { int v = off[i0] + b; off[i0] = v; cursor[i0] = v; }
    if (i1 < N_NODES) { int v = off[i1] + b; off[i1] = v; cursor[i1] = v; }
    if (blockIdx.x == 0 && t == 0) off[N_NODES] = N_EDGES;
}

__global__ __launch_bounds__(256) void fill_kernel(
        const int* __restrict__ src, const int* __restrict__ dst,
        int* __restrict__ cursor, int* __restrict__ eidx) {
    int e = blockIdx.x * 256 + threadIdx.x;
    if (e < N_EDGES) {
        int p = atomicAdd(&cursor[dst[e]], 1);
        eidx[p] = src[e];
    }
}

// ---------------- fused gather + GEMM1 + BN stats ----------------
// agg[n] = xin[n] + sum_{j in-edges} xin[src_j]; h[n] = agg[n] @ W1 + b1; stats over h
__global__ __launch_bounds__(256) void gin_gather_gemm_kernel(
        const float* __restrict__ xin, const int* __restrict__ off,
        const int* __restrict__ eidx, const float* __restrict__ W,
        const float* __restrict__ bias, float* __restrict__ h,
        float* __restrict__ stats_partial) {
    const int lane = threadIdx.x & 63;
    const int w    = threadIdx.x >> 6;

    float wcol[64];
#pragma unroll
    for (int k = 0; k < 64; ++k) wcol[k] = W[k * HID + lane];
    const float bs = bias[lane];

    float ssum = 0.f, ssumsq = 0.f;
    const int gw = blockIdx.x * 4 + w;
    const int stride = gridDim.x * 4;
    for (int n = gw; n < N_NODES; n += stride) {
        float v = xin[(size_t)n * HID + lane];   // (1+eps)*x self term, eps=0
        int beg = off[n], end = off[n + 1];
        int j = beg;
        for (; j + 4 <= end; j += 4) {
            int s0 = eidx[j], s1 = eidx[j + 1], s2 = eidx[j + 2], s3 = eidx[j + 3];
            float v0 = xin[(size_t)s0 * HID + lane];
            float v1 = xin[(size_t)s1 * HID + lane];
            float v2 = xin[(size_t)s2 * HID + lane];
            float v3 = xin[(size_t)s3 * HID + lane];
            v += (v0 + v1) + (v2 + v3);
        }
        for (; j < end; ++j) v += xin[(size_t)eidx[j] * HID + lane];

        float acc = bs;
#pragma unroll
        for (int k = 0; k < 64; ++k)
            acc = fmaf(bcastf(v, k), wcol[k], acc);
        h[(size_t)n * HID + lane] = acc;
        ssum += acc; ssumsq += acc * acc;
    }

    __shared__ float red[2][256];
    red[0][threadIdx.x] = ssum;
    red[1][threadIdx.x] = ssumsq;
    __syncthreads();
    if (w == 0) {
        float s = red[0][lane] + red[0][64 + lane] + red[0][128 + lane] + red[0][192 + lane];
        float q = red[1][lane] + red[1][64 + lane] + red[1][128 + lane] + red[1][192 + lane];
        stats_partial[(size_t)blockIdx.x * 128 + lane]      = s;
        stats_partial[(size_t)blockIdx.x * 128 + 64 + lane] = q;
    }
}

// ---------------- fused row-GEMM (as round 0) ----------------
template<bool PRE_BN, bool POST_RELU, bool ACCUM>
__global__ __launch_bounds__(256) void fused_gemm_kernel(
        const float* __restrict__ in, const float* __restrict__ W,
        const float* __restrict__ bias, const float* __restrict__ scale,
        const float* __restrict__ shift, float* __restrict__ out, int nrows) {
    const int lane = threadIdx.x & 63;
    const int w    = threadIdx.x >> 6;

    float wcol[64];
#pragma unroll
    for (int k = 0; k < 64; ++k) wcol[k] = W[k * HID + lane];

    float sc = 0.f, sh = 0.f, bs = 0.f;
    if (PRE_BN) { sc = scale[lane]; sh = shift[lane]; }
    if (!ACCUM) bs = bias[lane];

    const int gw = blockIdx.x * 4 + w;
    const int stride = gridDim.x * 4;
    for (int r = gw; r < nrows; r += stride) {
        float v = in[(size_t)r * HID + lane];
        if (PRE_BN) v = fmaxf(fmaf(sc, v, sh), 0.f);
        float acc = ACCUM ? out[(size_t)r * HID + lane] : bs;
#pragma unroll
        for (int k = 0; k < 64; ++k)
            acc = fmaf(bcastf(v, k), wcol[k], acc);
        if (POST_RELU) acc = fmaxf(acc, 0.f);
        out[(size_t)r * HID + lane] = acc;
    }
}

// ---------------- BN finalize ----------------
__global__ __launch_bounds__(64) void bn_finalize_kernel(
        const float* __restrict__ stats_partial, int nblocks,
        const float* __restrict__ gamma, const float* __restrict__ beta,
        float* __restrict__ scale, float* __restrict__ shift) {
    int c = threadIdx.x;
    float s = 0.f, q = 0.f;
    for (int b = 0; b < nblocks; ++b) {
        s += stats_partial[(size_t)b * 128 + c];
        q += stats_partial[(size_t)b * 128 + 64 + c];
    }
    float mean = s / (float)N_NODES;
    float var  = q / (float)N_NODES - mean * mean;
    float scl  = gamma[c] * rsqrtf(var + BN_EPS);
    scale[c] = scl;
    shift[c] = beta[c] - mean * scl;
}

extern "C" void kernel_launch(void* const* d_in, const int* in_sizes, int n_in,
                              void* d_out, int out_size, void* d_ws, size_t ws_size,
                              hipStream_t stream) {
    const float* x    = (const float*)d_in[0];
    const int*   ei   = (const int*)d_in[1];
    const int*   src  = ei;
    const int*   dst  = ei + N_EDGES;
    const float* W1_0 = (const float*)d_in[3];
    const float* b1_0 = (const float*)d_in[4];
    const float* g_0  = (const float*)d_in[5];
    const float* be_0 = (const float*)d_in[6];
    const float* W2_0 = (const float*)d_in[7];
    const float* b2_0 = (const float*)d_in[8];
    const float* W1_1 = (const float*)d_in[9];
    const float* b1_1 = (const float*)d_in[10];
    const float* g_1  = (const float*)d_in[11];
    const float* be_1 = (const float*)d_in[12];
    const float* W2_1 = (const float*)d_in[13];
    const float* b2_1 = (const float*)d_in[14];
    const float* Wjk  = (const float*)d_in[15];
    const float* bjk  = (const float*)d_in[16];

    const size_t FEAT = (size_t)N_NODES * HID;

    float* tmp   = (float*)d_ws;                       // FEAT (pre-BN h, then h2 in-place)
    float* h1    = tmp + FEAT;                         // FEAT
    float* stats = h1 + FEAT;                          // GATHER_BLOCKS * 128
    float* scale = stats + (size_t)GATHER_BLOCKS * 128;
    float* shift = scale + 64;
    int*   deg    = (int*)(shift + 64);                // N_NODES
    int*   off    = deg + N_NODES;                     // N_NODES + 1 (pad 2)
    int*   cursor = off + N_NODES + 2;                 // N_NODES
    int*   bsums  = cursor + N_NODES;                  // 256
    int*   eidx   = bsums + 256;                       // N_EDGES
    float* out    = (float*)d_out;

    const int edge_blocks = (N_EDGES + 255) / 256;

    // ---------------- CSR build (once; reused by both layers) ----------------
    hipMemsetAsync(deg, 0, N_NODES * sizeof(int), stream);
    hist_kernel<<<edge_blocks, 256, 0, stream>>>(dst, deg);
    scan_partial_kernel<<<SCAN_BLOCKS, 256, 0, stream>>>(deg, off, bsums);
    scan_bsums_kernel<<<1, 256, 0, stream>>>(bsums);
    scan_addback_kernel<<<SCAN_BLOCKS, 256, 0, stream>>>(off, cursor, bsums);
    fill_kernel<<<edge_blocks, 256, 0, stream>>>(src, dst, cursor, eidx);

    // ---------------- layer 0 ----------------
    gin_gather_gemm_kernel<<<GATHER_BLOCKS, 256, 0, stream>>>(
        x, off, eidx, W1_0, b1_0, tmp, stats);
    bn_finalize_kernel<<<1, 64, 0, stream>>>(stats, GATHER_BLOCKS, g_0, be_0, scale, shift);
    fused_gemm_kernel<true, true, false><<<GEMM_BLOCKS, 256, 0, stream>>>(
        tmp, W2_0, b2_0, scale, shift, h1, N_NODES);

    // ---------------- layer 1 ----------------
    gin_gather_gemm_kernel<<<GATHER_BLOCKS, 256, 0, stream>>>(
        h1, off, eidx, W1_1, b1_1, tmp, stats);
    bn_finalize_kernel<<<1, 64, 0, stream>>>(stats, GATHER_BLOCKS, g_1, be_1, scale, shift);
    fused_gemm_kernel<true, true, false><<<GEMM_BLOCKS, 256, 0, stream>>>(
        tmp, W2_1, b2_1, scale, shift, tmp, N_NODES);   // in-place: tmp becomes h2

    // ---------------- jump head: out = [x|h1|h2] @ Wjk + bjk ----------------
    fused_gemm_kernel<false, false, false><<<GEMM_BLOCKS, 256, 0, stream>>>(
        x, Wjk, bjk, nullptr, nullptr, out, N_NODES);
    fused_gemm_kernel<false, false, true><<<GEMM_BLOCKS, 256, 0, stream>>>(
        h1, Wjk + (size_t)64 * HID, nullptr, nullptr, nullptr, out, N_NODES);
    fused_gemm_kernel<false, false, true><<<GEMM_BLOCKS, 256, 0, stream>>>(
        tmp, Wjk + (size_t)128 * HID, nullptr, nullptr, nullptr, out, N_NODES);
}

// Round 3
// 657.346 us; speedup vs baseline: 5.2311x; 2.3605x over previous
//
#include <hip/hip_runtime.h>

#define N_NODES 100000
#define N_EDGES 1600000
#define HID 64
#define BN_EPS 1e-5f

#define GEMM_BLOCKS 1024     // 256 threads = 4 waves each
#define GATHER_BLOCKS 2048
#define SCAN_CHUNK 512
#define SCAN_BLOCKS ((N_NODES + SCAN_CHUNK - 1) / SCAN_CHUNK)   // 196

__device__ __forceinline__ float bcastf(float v, int k) {
    return __int_as_float(__builtin_amdgcn_readlane(__float_as_int(v), k));
}

// ---------------- CSR build ----------------
__global__ __launch_bounds__(256) void hist_kernel(
        const int* __restrict__ dst, int* __restrict__ deg) {
    int e = blockIdx.x * 256 + threadIdx.x;
    if (e < N_EDGES) atomicAdd(&deg[dst[e]], 1);
}

// block-local exclusive scan of 512 elements (2 per thread)
__global__ __launch_bounds__(256) void scan_partial_kernel(
        const int* __restrict__ deg, int* __restrict__ off, int* __restrict__ bsums) {
    __shared__ int sd[256];
    int t = threadIdx.x;
    int base = blockIdx.x * SCAN_CHUNK;
    int i0 = base + 2 * t, i1 = i0 + 1;
    int d0 = (i0 < N_NODES) ? deg[i0] : 0;
    int d1 = (i1 < N_NODES) ? deg[i1] : 0;
    sd[t] = d0 + d1;
    __syncthreads();
    for (int o = 1; o < 256; o <<= 1) {
        int v = (t >= o) ? sd[t - o] : 0;
        __syncthreads();
        sd[t] += v;
        __syncthreads();
    }
    int excl = sd[t] - (d0 + d1);   // exclusive within block
    if (i0 < N_NODES) off[i0] = excl;
    if (i1 < N_NODES) off[i1] = excl + d0;
    if (t == 255) bsums[blockIdx.x] = sd[255];
}

__global__ __launch_bounds__(256) void scan_bsums_kernel(int* __restrict__ bsums) {
    __shared__ int sd[256];
    int t = threadIdx.x;
    int v = (t < SCAN_BLOCKS) ? bsums[t] : 0;
    sd[t] = v;
    __syncthreads();
    for (int o = 1; o < 256; o <<= 1) {
        int u = (t >= o) ? sd[t - o] : 0;
        __syncthreads();
        sd[t] += u;
        __syncthreads();
    }
    if (t < SCAN_BLOCKS) bsums[t] = sd[t] - v;   // exclusive
}

__global__ __launch_bounds__(256) void scan_addback_kernel(
        int* __restrict__ off, int* __restrict__ cursor, const int* __restrict__ bsums) {
    int t = threadIdx.x;
    int b = bsums[blockIdx.x];
    int base = blockIdx.x * SCAN_CHUNK;
    int i0 = base + 2 * t, i1 = i0 + 1;
    if (i0 < N_NODES) { int v = off[i0] + b; off[i0] = v; cursor[i0] = v; }
    if (i1 < N_NODES) { int v = off[i1] + b; off[i1] = v; cursor[i1] = v; }
    if (blockIdx.x == 0 && t == 0) off[N_NODES] = N_EDGES;
}

__global__ __launch_bounds__(256) void fill_kernel(
        const int* __restrict__ src, const int* __restrict__ dst,
        int* __restrict__ cursor, int* __restrict__ eidx) {
    int e = blockIdx.x * 256 + threadIdx.x;
    if (e < N_EDGES) {
        int p = atomicAdd(&cursor[dst[e]], 1);
        eidx[p] = src[e];
    }
}

// ---------------- fused gather + GEMM1 + BN stats ----------------
// agg[n] = xin[n] + sum_{j in-edges} xin[src_j]; h[n] = agg[n] @ W1 + b1; stats over h
__global__ __launch_bounds__(256) void gin_gather_gemm_kernel(
        const float* __restrict__ xin, const int* __restrict__ off,
        const int* __restrict__ eidx, const float* __restrict__ W,
        const float* __restrict__ bias, float* __restrict__ h,
        float* __restrict__ stats_partial) {
    const int lane = threadIdx.x & 63;
    const int w    = threadIdx.x >> 6;

    float wcol[64];
#pragma unroll
    for (int k = 0; k < 64; ++k) wcol[k] = W[k * HID + lane];
    const float bs = bias[lane];

    float ssum = 0.f, ssumsq = 0.f;
    const int gw = blockIdx.x * 4 + w;
    const int stride = gridDim.x * 4;
    for (int n = gw; n < N_NODES; n += stride) {
        float v = xin[(size_t)n * HID + lane];   // (1+eps)*x self term, eps=0
        int beg = off[n], end = off[n + 1];
        int j = beg;
        for (; j + 4 <= end; j += 4) {
            int s0 = eidx[j], s1 = eidx[j + 1], s2 = eidx[j + 2], s3 = eidx[j + 3];
            float v0 = xin[(size_t)s0 * HID + lane];
            float v1 = xin[(size_t)s1 * HID + lane];
            float v2 = xin[(size_t)s2 * HID + lane];
            float v3 = xin[(size_t)s3 * HID + lane];
            v += (v0 + v1) + (v2 + v3);
        }
        for (; j < end; ++j) v += xin[(size_t)eidx[j] * HID + lane];

        float acc = bs;
#pragma unroll
        for (int k = 0; k < 64; ++k)
            acc = fmaf(bcastf(v, k), wcol[k], acc);
        h[(size_t)n * HID + lane] = acc;
        ssum += acc; ssumsq += acc * acc;
    }

    __shared__ float red[2][256];
    red[0][threadIdx.x] = ssum;
    red[1][threadIdx.x] = ssumsq;
    __syncthreads();
    if (w == 0) {
        float s = red[0][lane] + red[0][64 + lane] + red[0][128 + lane] + red[0][192 + lane];
        float q = red[1][lane] + red[1][64 + lane] + red[1][128 + lane] + red[1][192 + lane];
        stats_partial[(size_t)blockIdx.x * 128 + lane]      = s;
        stats_partial[(size_t)blockIdx.x * 128 + 64 + lane] = q;
    }
}

// ---------------- fused row-GEMM ----------------
template<bool PRE_BN, bool POST_RELU, bool ACCUM>
__global__ __launch_bounds__(256) void fused_gemm_kernel(
        const float* __restrict__ in, const float* __restrict__ W,
        const float* __restrict__ bias, const float* __restrict__ scale,
        const float* __restrict__ shift, float* __restrict__ out, int nrows) {
    const int lane = threadIdx.x & 63;
    const int w    = threadIdx.x >> 6;

    float wcol[64];
#pragma unroll
    for (int k = 0; k < 64; ++k) wcol[k] = W[k * HID + lane];

    float sc = 0.f, sh = 0.f, bs = 0.f;
    if (PRE_BN) { sc = scale[lane]; sh = shift[lane]; }
    if (!ACCUM) bs = bias[lane];

    const int gw = blockIdx.x * 4 + w;
    const int stride = gridDim.x * 4;
    for (int r = gw; r < nrows; r += stride) {
        float v = in[(size_t)r * HID + lane];
        if (PRE_BN) v = fmaxf(fmaf(sc, v, sh), 0.f);
        float acc = ACCUM ? out[(size_t)r * HID + lane] : bs;
#pragma unroll
        for (int k = 0; k < 64; ++k)
            acc = fmaf(bcastf(v, k), wcol[k], acc);
        if (POST_RELU) acc = fmaxf(acc, 0.f);
        out[(size_t)r * HID + lane] = acc;
    }
}

// ---------------- BN finalize: parallel reduce of partials ----------------
// 1024 threads (16 waves): thread (c = t&63, chunk = t>>6) sums a strided
// 1/16th of the nblocks partials, then LDS tree + scale/shift epilogue.
__global__ __launch_bounds__(1024) void bn_finalize_kernel(
        const float* __restrict__ stats_partial, int nblocks,
        const float* __restrict__ gamma, const float* __restrict__ beta,
        float* __restrict__ scale, float* __restrict__ shift) {
    __shared__ float red[2][1024];
    const int t = threadIdx.x;
    const int c = t & 63;
    const int chunk = t >> 6;        // 0..15
    float s = 0.f, q = 0.f;
    for (int b = chunk; b < nblocks; b += 16) {
        s += stats_partial[(size_t)b * 128 + c];
        q += stats_partial[(size_t)b * 128 + 64 + c];
    }
    red[0][t] = s;
    red[1][t] = q;
    __syncthreads();
    if (chunk == 0) {
        float ss = 0.f, qq = 0.f;
#pragma unroll
        for (int k = 0; k < 16; ++k) {
            ss += red[0][k * 64 + c];
            qq += red[1][k * 64 + c];
        }
        float mean = ss / (float)N_NODES;
        float var  = qq / (float)N_NODES - mean * mean;
        float scl  = gamma[c] * rsqrtf(var + BN_EPS);
        scale[c] = scl;
        shift[c] = beta[c] - mean * scl;
    }
}

extern "C" void kernel_launch(void* const* d_in, const int* in_sizes, int n_in,
                              void* d_out, int out_size, void* d_ws, size_t ws_size,
                              hipStream_t stream) {
    const float* x    = (const float*)d_in[0];
    const int*   ei   = (const int*)d_in[1];
    const int*   src  = ei;
    const int*   dst  = ei + N_EDGES;
    const float* W1_0 = (const float*)d_in[3];
    const float* b1_0 = (const float*)d_in[4];
    const float* g_0  = (const float*)d_in[5];
    const float* be_0 = (const float*)d_in[6];
    const float* W2_0 = (const float*)d_in[7];
    const float* b2_0 = (const float*)d_in[8];
    const float* W1_1 = (const float*)d_in[9];
    const float* b1_1 = (const float*)d_in[10];
    const float* g_1  = (const float*)d_in[11];
    const float* be_1 = (const float*)d_in[12];
    const float* W2_1 = (const float*)d_in[13];
    const float* b2_1 = (const float*)d_in[14];
    const float* Wjk  = (const float*)d_in[15];
    const float* bjk  = (const float*)d_in[16];

    const size_t FEAT = (size_t)N_NODES * HID;

    float* tmp   = (float*)d_ws;                       // FEAT (pre-BN h, then h2 in-place)
    float* h1    = tmp + FEAT;                         // FEAT
    float* stats = h1 + FEAT;                          // GATHER_BLOCKS * 128
    float* scale = stats + (size_t)GATHER_BLOCKS * 128;
    float* shift = scale + 64;
    int*   deg    = (int*)(shift + 64);                // N_NODES
    int*   off    = deg + N_NODES;                     // N_NODES + 1 (pad 2)
    int*   cursor = off + N_NODES + 2;                 // N_NODES
    int*   bsums  = cursor + N_NODES;                  // 256
    int*   eidx   = bsums + 256;                       // N_EDGES
    float* out    = (float*)d_out;

    const int edge_blocks = (N_EDGES + 255) / 256;

    // ---------------- CSR build (once; reused by both layers) ----------------
    hipMemsetAsync(deg, 0, N_NODES * sizeof(int), stream);
    hist_kernel<<<edge_blocks, 256, 0, stream>>>(dst, deg);
    scan_partial_kernel<<<SCAN_BLOCKS, 256, 0, stream>>>(deg, off, bsums);
    scan_bsums_kernel<<<1, 256, 0, stream>>>(bsums);
    scan_addback_kernel<<<SCAN_BLOCKS, 256, 0, stream>>>(off, cursor, bsums);
    fill_kernel<<<edge_blocks, 256, 0, stream>>>(src, dst, cursor, eidx);

    // ---------------- layer 0 ----------------
    gin_gather_gemm_kernel<<<GATHER_BLOCKS, 256, 0, stream>>>(
        x, off, eidx, W1_0, b1_0, tmp, stats);
    bn_finalize_kernel<<<1, 1024, 0, stream>>>(stats, GATHER_BLOCKS, g_0, be_0, scale, shift);
    fused_gemm_kernel<true, true, false><<<GEMM_BLOCKS, 256, 0, stream>>>(
        tmp, W2_0, b2_0, scale, shift, h1, N_NODES);

    // ---------------- layer 1 ----------------
    gin_gather_gemm_kernel<<<GATHER_BLOCKS, 256, 0, stream>>>(
        h1, off, eidx, W1_1, b1_1, tmp, stats);
    bn_finalize_kernel<<<1, 1024, 0, stream>>>(stats, GATHER_BLOCKS, g_1, be_1, scale, shift);
    fused_gemm_kernel<true, true, false><<<GEMM_BLOCKS, 256, 0, stream>>>(
        tmp, W2_1, b2_1, scale, shift, tmp, N_NODES);   // in-place: tmp becomes h2

    // ---------------- jump head: out = [x|h1|h2] @ Wjk + bjk ----------------
    fused_gemm_kernel<false, false, false><<<GEMM_BLOCKS, 256, 0, stream>>>(
        x, Wjk, bjk, nullptr, nullptr, out, N_NODES);
    fused_gemm_kernel<false, false, true><<<GEMM_BLOCKS, 256, 0, stream>>>(
        h1, Wjk + (size_t)64 * HID, nullptr, nullptr, nullptr, out, N_NODES);
    fused_gemm_kernel<false, false, true><<<GEMM_BLOCKS, 256, 0, stream>>>(
        tmp, Wjk + (size_t)128 * HID, nullptr, nullptr, nullptr, out, N_NODES);
}